// Round 14
// baseline (136.407 us; speedup 1.0000x reference)
//
#include <hip/hip_runtime.h>
#include <hip/hip_bf16.h>
#include <math.h>

// Problem constants
#define VOCAB 30522
#define EMB 768
#define MAXPOS 512
#define HID 512
#define IMG 2048
#define ATT 256
#define BB 32
#define LL 512
#define SS 6
#define HL 128
#define LN_EPS 1e-12f
#define KCH 128
#define NROWS (BB * LL)
#define MPS (BB + BB * SS)   // 224 rows: img_pred(32) + sep_images(192)

typedef __bf16 bf16_t;
typedef __attribute__((ext_vector_type(4))) __bf16 bf16x4;
typedef __attribute__((ext_vector_type(8))) __bf16 bf16x8;
typedef __attribute__((ext_vector_type(4))) float f32x4;

#define AS1 __attribute__((address_space(1)))
#define AS3 __attribute__((address_space(3)))
__device__ __forceinline__ void gload_lds16(const bf16_t* g, bf16_t* l) {
    __builtin_amdgcn_global_load_lds((const AS1 void*)g, (AS3 void*)l, 16, 0, 0);
}

__device__ __forceinline__ float wave_sum(float v) {
    v += __shfl_xor(v, 1);  v += __shfl_xor(v, 2);  v += __shfl_xor(v, 4);
    v += __shfl_xor(v, 8);  v += __shfl_xor(v, 16); v += __shfl_xor(v, 32);
    return v;
}
__device__ __forceinline__ float wave_max(float v) {
    v = fmaxf(v, __shfl_xor(v, 1));  v = fmaxf(v, __shfl_xor(v, 2));
    v = fmaxf(v, __shfl_xor(v, 4));  v = fmaxf(v, __shfl_xor(v, 8));
    v = fmaxf(v, __shfl_xor(v, 16)); v = fmaxf(v, __shfl_xor(v, 32));
    return v;
}

// ================= device building blocks =================

// ---- BERT embed + LN, TWO rows per wave (doubled loads-in-flight) ----
__device__ void dev_embed2(int r0, const int* __restrict__ ids,
                           const float* __restrict__ we, const float* __restrict__ pe,
                           const float* __restrict__ te, const float* __restrict__ g,
                           const float* __restrict__ bta, bf16_t* __restrict__ out) {
    int lane = threadIdx.x & 63;
    int r1 = r0 + 1;
    int id0 = ids[r0], id1 = ids[r1];
    const float* w0 = we + (size_t)id0 * EMB + lane * 12;
    const float* p0 = pe + (size_t)(r0 & (LL - 1)) * EMB + lane * 12;
    const float* w1 = we + (size_t)id1 * EMB + lane * 12;
    const float* p1 = pe + (size_t)(r1 & (LL - 1)) * EMB + lane * 12;
    const float* tp = te + lane * 12;
    float4 a0[3], b0[3], a1[3], b1[3], c[3];
#pragma unroll
    for (int q = 0; q < 3; q++) {
        a0[q] = *(const float4*)(w0 + q * 4);
        a1[q] = *(const float4*)(w1 + q * 4);
        b0[q] = *(const float4*)(p0 + q * 4);
        b1[q] = *(const float4*)(p1 + q * 4);
        c[q]  = *(const float4*)(tp + q * 4);
    }
    const float* gp = g + lane * 12;
    const float* bp = bta + lane * 12;
#pragma unroll
    for (int rr = 0; rr < 2; rr++) {
        float4* av = rr ? a1 : a0;
        float4* bv = rr ? b1 : b0;
        int r = rr ? r1 : r0;
        float x[12]; float s = 0.f, ss = 0.f;
#pragma unroll
        for (int q = 0; q < 3; q++) {
            float v0 = av[q].x + bv[q].x + c[q].x;
            float v1 = av[q].y + bv[q].y + c[q].y;
            float v2 = av[q].z + bv[q].z + c[q].z;
            float v3 = av[q].w + bv[q].w + c[q].w;
            x[q * 4 + 0] = v0; x[q * 4 + 1] = v1;
            x[q * 4 + 2] = v2; x[q * 4 + 3] = v3;
            s += v0 + v1 + v2 + v3;
            ss += v0 * v0 + v1 * v1 + v2 * v2 + v3 * v3;
        }
        s = wave_sum(s); ss = wave_sum(ss);
        float mu = s * (1.0f / EMB);
        float var = ss * (1.0f / EMB) - mu * mu;
        float rs = rsqrtf(var + LN_EPS);
        bf16_t* orow = out + (size_t)r * EMB + lane * 12;
#pragma unroll
        for (int q = 0; q < 3; q++) {
            float4 gv = *(const float4*)(gp + q * 4);
            float4 bb = *(const float4*)(bp + q * 4);
            bf16x4 y;
            y[0] = (bf16_t)(gv.x * (x[q * 4 + 0] - mu) * rs + bb.x);
            y[1] = (bf16_t)(gv.y * (x[q * 4 + 1] - mu) * rs + bb.y);
            y[2] = (bf16_t)(gv.z * (x[q * 4 + 2] - mu) * rs + bb.z);
            y[3] = (bf16_t)(gv.w * (x[q * 4 + 3] - mu) * rs + bb.w);
            *(bf16x4*)(orow + q * 4) = y;
        }
    }
}

// ---- tiled transpose+bf16 of one 32x32 tile ----
__device__ void dev_conv(const float* __restrict__ in, bf16_t* __restrict__ out,
                         int K, int N, int x, int y, char* smem) {
    float (*t)[33] = (float(*)[33])smem;
    int n0 = x * 32, k0 = y * 32;
    int tx = threadIdx.x & 31, ty = threadIdx.x >> 5;
#pragma unroll
    for (int i = 0; i < 4; i++)
        t[ty + i * 8][tx] = in[(size_t)(k0 + ty + i * 8) * N + n0 + tx];
    __syncthreads();
#pragma unroll
    for (int i = 0; i < 4; i++)
        out[(size_t)(n0 + ty + i * 8) * K + k0 + tx] = (bf16_t)t[tx][ty + i * 8];
}

// ---- history embed+LN partial sums, software-pipelined word_emb gather ----
__device__ void dev_hist(int bs, int grp, const int* __restrict__ ids,
                         const int* __restrict__ lens,
                         const float* __restrict__ we, const float* __restrict__ pe,
                         const float* __restrict__ te, const float* __restrict__ g,
                         const float* __restrict__ bta,
                         float* __restrict__ parts, char* smem) {
    float (*acc)[EMB] = (float(*)[EMB])smem;
    int len = lens[bs];
    int tid = threadIdx.x, wid = tid >> 6, lane = tid & 63;
#pragma unroll
    for (int k = 0; k < 12; k++) acc[wid][lane + k * 64] = 0.f;
    // te is reused by every token: preload into regs
    float tv[12];
#pragma unroll
    for (int k = 0; k < 12; k++) tv[k] = te[lane + k * 64];
    // prologue: issue token 0's word_emb gather
    int h = grp + 8 * wid;
    bool valid = (h < len);
    float xw[12];
    {
        int id = valid ? ids[bs * HL + h] : 0;
        const float* wrow = we + (size_t)id * EMB;
        if (valid) {
#pragma unroll
            for (int k = 0; k < 12; k++) xw[k] = wrow[lane + k * 64];
        }
    }
#pragma unroll
    for (int i = 0; i < 4; i++) {
        // prefetch next token's word row while computing current
        int hn = h + 32;
        bool vnext = (i < 3) && (hn < len);
        float yw[12];
        {
            int idn = vnext ? ids[bs * HL + hn] : 0;
            const float* wrown = we + (size_t)idn * EMB;
            if (vnext) {
#pragma unroll
                for (int k = 0; k < 12; k++) yw[k] = wrown[lane + k * 64];
            }
        }
        if (valid) {
            const float* prow = pe + (size_t)h * EMB;
            float x[12]; float s = 0.f, ss = 0.f;
#pragma unroll
            for (int k = 0; k < 12; k++) {
                int j = lane + k * 64;
                float v = xw[k] + prow[j] + tv[k];
                x[k] = v; s += v; ss += v * v;
            }
            s = wave_sum(s); ss = wave_sum(ss);
            float mu = s * (1.0f / EMB);
            float var = ss * (1.0f / EMB) - mu * mu;
            float rs = rsqrtf(var + LN_EPS);
#pragma unroll
            for (int k = 0; k < 12; k++) {
                int j = lane + k * 64;
                acc[wid][j] += g[j] * (x[k] - mu) * rs + bta[j];
            }
        }
#pragma unroll
        for (int k = 0; k < 12; k++) xw[k] = yw[k];
        valid = vnext;
        h = hn;
    }
    __syncthreads();
    float* dst = parts + ((size_t)grp * (BB * SS) + bs) * EMB;
    for (int j = tid; j < EMB; j += 256)
        dst[j] = acc[0][j] + acc[1][j] + acc[2][j] + acc[3][j];
}

// ---- split-K thin GEMM with A-prologue modes (16 rows/block) ----
// AMODE 0: direct A; AMODE 1: relu(sum16 parts + abias); AMODE 2: (sum8 parts)/len
template <int AMODE>
__device__ void dev_thin(int bx, int by, int bz,
                         const float* __restrict__ A, int lda,
                         const float* __restrict__ parts, size_t MNp,
                         const float* __restrict__ abias,
                         const int* __restrict__ lens,
                         const float* __restrict__ B, int ldb,
                         float* __restrict__ part, int M, int N, char* smem) {
    float (*As)[KCH] = (float(*)[KCH])smem;
    int tid = threadIdx.x;
    int n0 = bx * 256, m0 = by * 16, k0 = bz * KCH;

    if (AMODE == 0) {
#pragma unroll
        for (int i = 0; i < 2; i++) {
            int lin = (i * 256 + tid) * 4;
            int m = lin >> 7, k = lin & (KCH - 1);
            *(float4*)&As[m][k] = *(const float4*)(A + (size_t)(m0 + m) * lda + k0 + k);
        }
    } else if (AMODE == 1) {
#pragma unroll
        for (int i = 0; i < 2; i++) {
            int f = i * 256 + tid;
            int m = f >> 5, kq = (f & 31) * 4;
            int row = m0 + m;
            float4 v = *(const float4*)(abias + k0 + kq);
#pragma unroll
            for (int ks = 0; ks < 16; ks++) {
                float4 p = *(const float4*)(parts + (size_t)ks * MNp +
                                            (size_t)row * 512 + k0 + kq);
                v.x += p.x; v.y += p.y; v.z += p.z; v.w += p.w;
            }
            v.x = fmaxf(v.x, 0.f); v.y = fmaxf(v.y, 0.f);
            v.z = fmaxf(v.z, 0.f); v.w = fmaxf(v.w, 0.f);
            *(float4*)&As[m][kq] = v;
        }
    } else {
#pragma unroll
        for (int i = 0; i < 2; i++) {
            int f = i * 256 + tid;
            int m = f >> 5, kq = (f & 31) * 4;
            int row = m0 + m;
            float invd = 1.0f / fmaxf((float)lens[row], 1.0f);
            float4 v = {};
#pragma unroll
            for (int gg = 0; gg < 8; gg++) {
                float4 p = *(const float4*)(parts + (size_t)gg * MNp +
                                            (size_t)row * EMB + k0 + kq);
                v.x += p.x; v.y += p.y; v.z += p.z; v.w += p.w;
            }
            As[m][kq + 0] = v.x * invd; As[m][kq + 1] = v.y * invd;
            As[m][kq + 2] = v.z * invd; As[m][kq + 3] = v.w * invd;
        }
    }
    __syncthreads();
    int nq = tid & 63, mg = tid >> 6;
    const float* Bp = B + (size_t)k0 * ldb + n0 + nq * 4;
    float4 acc[4] = {};
    for (int kk = 0; kk < KCH; kk += 8) {
        float4 b0 = *(const float4*)(Bp + (size_t)(kk + 0) * ldb);
        float4 b1 = *(const float4*)(Bp + (size_t)(kk + 1) * ldb);
        float4 b2 = *(const float4*)(Bp + (size_t)(kk + 2) * ldb);
        float4 b3 = *(const float4*)(Bp + (size_t)(kk + 3) * ldb);
        float4 b4 = *(const float4*)(Bp + (size_t)(kk + 4) * ldb);
        float4 b5 = *(const float4*)(Bp + (size_t)(kk + 5) * ldb);
        float4 b6 = *(const float4*)(Bp + (size_t)(kk + 6) * ldb);
        float4 b7 = *(const float4*)(Bp + (size_t)(kk + 7) * ldb);
        float4 bv[8] = {b0, b1, b2, b3, b4, b5, b6, b7};
#pragma unroll
        for (int j = 0; j < 8; j++) {
#pragma unroll
            for (int mi = 0; mi < 4; mi++) {
                float a = As[mg * 4 + mi][kk + j];
                acc[mi].x += a * bv[j].x; acc[mi].y += a * bv[j].y;
                acc[mi].z += a * bv[j].z; acc[mi].w += a * bv[j].w;
            }
        }
    }
    size_t MN = (size_t)M * N;
#pragma unroll
    for (int mi = 0; mi < 4; mi++)
        *(float4*)(part + (size_t)bz * MN +
                   (size_t)(m0 + mg * 4 + mi) * N + n0 + nq * 4) = acc[mi];
}

// ---- MFMA bf16 GEMM 128x128 tile, BK=32, gload_lds + dbuf ----
template <int ACT, bool OBF16, bool ROWADD4, bool FUSE_ATT>
__device__ void dev_mfma(int bx, int by,
                         const bf16_t* __restrict__ A, const bf16_t* __restrict__ Bt,
                         const float* __restrict__ bias,
                         const float* __restrict__ rowadd,
                         void* __restrict__ Cv,
                         const float* __restrict__ w2, float* __restrict__ att_part,
                         int M, int N, int K, char* smem) {
    bf16_t* As = (bf16_t*)smem;                 // [2][4096]
    bf16_t* Bs = (bf16_t*)(smem + 16384);       // [2][4096]
    float (*attp)[2] = (float(*)[2])(smem + 32768);
    int tid = threadIdx.x;
    int lane = tid & 63, wid = tid >> 6;
    int wr = wid >> 1, wc = wid & 1;
    int row0 = by * 128, col0 = bx * 128;

    int srow = tid >> 2;
    int sslot = tid & 3;

    const bf16_t* Ag = A + (size_t)row0 * K;
    const bf16_t* Bg = Bt + (size_t)col0 * K;

    f32x4 acc[4][4] = {};
    int lrow = lane & 15;
    int g8 = lane >> 4;

    auto stage_pair = [&](int buf, int kb) {
#pragma unroll
        for (int rr = 0; rr < 2; rr++) {
            int r = srow + rr * 64;
            int sl = sslot ^ ((r >> 1) & 3);
            gload_lds16(Ag + (size_t)r * K + kb + sl * 8,
                        As + buf * 4096 + wid * 512 + rr * 2048);
            gload_lds16(Bg + (size_t)r * K + kb + sl * 8,
                        Bs + buf * 4096 + wid * 512 + rr * 2048);
        }
    };

    stage_pair(0, 0);
    __syncthreads();
    int cur = 0;
    for (int kb = 0; kb < K; kb += 32) {
        if (kb + 32 < K) stage_pair(cur ^ 1, kb + 32);
        bf16x8 af[4], bfr[4];
#pragma unroll
        for (int mi = 0; mi < 4; mi++) {
            int r = wr * 64 + mi * 16 + lrow;
            int sl = g8 ^ ((r >> 1) & 3);
            af[mi] = *(const bf16x8*)(As + cur * 4096 + r * 32 + sl * 8);
        }
#pragma unroll
        for (int ni = 0; ni < 4; ni++) {
            int r = wc * 64 + ni * 16 + lrow;
            int sl = g8 ^ ((r >> 1) & 3);
            bfr[ni] = *(const bf16x8*)(Bs + cur * 4096 + r * 32 + sl * 8);
        }
#pragma unroll
        for (int mi = 0; mi < 4; mi++)
#pragma unroll
            for (int ni = 0; ni < 4; ni++)
                acc[mi][ni] = __builtin_amdgcn_mfma_f32_16x16x32_bf16(
                    af[mi], bfr[ni], acc[mi][ni], 0, 0, 0);
        __syncthreads();
        cur ^= 1;
    }

    if (FUSE_ATT) {
        float w2v[4];
#pragma unroll
        for (int ni = 0; ni < 4; ni++)
            w2v[ni] = w2[col0 + wc * 64 + ni * 16 + lrow];
#pragma unroll
        for (int mi = 0; mi < 4; mi++) {
#pragma unroll
            for (int r = 0; r < 4; r++) {
                float s = 0.f;
#pragma unroll
                for (int ni = 0; ni < 4; ni++) {
                    int col = col0 + wc * 64 + ni * 16 + lrow;
                    float v = tanhf(acc[mi][ni][r] + bias[col]);
                    s += v * w2v[ni];
                }
                s += __shfl_xor(s, 1); s += __shfl_xor(s, 2);
                s += __shfl_xor(s, 4); s += __shfl_xor(s, 8);
                if ((lane & 15) == 0)
                    attp[wr * 64 + mi * 16 + (lane >> 4) * 4 + r][wc] = s;
            }
        }
        __syncthreads();
        if (tid < 128)
            att_part[(size_t)bx * M + row0 + tid] = attp[tid][0] + attp[tid][1];
        return;
    }

    float* Cf = (float*)Cv;
    bf16_t* Cb = (bf16_t*)Cv;
    int rg = (lane >> 4) * 4;
#pragma unroll
    for (int mi = 0; mi < 4; mi++) {
#pragma unroll
        for (int ni = 0; ni < 4; ni++) {
            int col = col0 + wc * 64 + ni * 16 + lrow;
#pragma unroll
            for (int r = 0; r < 4; r++) {
                int row = row0 + wr * 64 + mi * 16 + rg + r;
                float v = acc[mi][ni][r] + bias[col];
                if (ROWADD4) {
                    int bslot = row >> 9;
#pragma unroll
                    for (int ks = 0; ks < 4; ks++)
                        v += rowadd[(size_t)ks * BB * HID + (size_t)bslot * HID + col];
                }
                if (ACT == 1) v = fmaxf(v, 0.f);
                if (ACT == 2) v = tanhf(v);
                if (OBF16) Cb[(size_t)row * N + col] = (bf16_t)v;
                else       Cf[(size_t)row * N + col] = v;
            }
        }
    }
}

// ================= dispatch kernels =================

// D1 (longest-job-first): thin-sep(384) | thin-img(64) | hist(1536) | conv(768) | embed(2048)
#define F1_SEP   384
#define F1_IMG   (F1_SEP + 64)     // 448
#define F1_HIST  (F1_IMG + 1536)   // 1984
#define F1_CONV  (F1_HIST + 768)   // 2752
#define F1_EMB   (F1_CONV + 2048)  // 4800
__global__ __launch_bounds__(256)
void uber_pre(const int* input_text, const int* prev_hist, const int* prev_hist_ln,
              const float* word_emb, const float* pos_emb, const float* type_emb,
              const float* ln_g, const float* ln_b,
              const float* W_e2h, bf16_t* Wt_e2h,
              const float* W_mm, bf16_t* Wt_mm,
              const float* W_a1, bf16_t* Wt_a1,
              const float* img_pred, const float* sep_images,
              const float* W_img, const float* W_sep,
              bf16_t* reps_bf, float* hist_parts, float* partA) {
    __shared__ __align__(16) char smem[12288];
    int bid = blockIdx.x;
    if (bid < F1_SEP) {
        int l = bid;            // 384: (2n,12m,16z)
        int l2 = l >> 1;
        dev_thin<0>(l & 1, l2 % 12, l2 / 12, sep_images, IMG,
                    nullptr, 0, nullptr, nullptr, W_sep, HID,
                    partA + (size_t)BB * HID, MPS, HID, smem);
    } else if (bid < F1_IMG) {
        int l = bid - F1_SEP;   // 64: (2n,2m,16z)
        dev_thin<0>(l & 1, (l >> 1) & 1, l >> 2, img_pred, IMG,
                    nullptr, 0, nullptr, nullptr, W_img, HID, partA, MPS, HID, smem);
    } else if (bid < F1_HIST) {
        int b = bid - F1_IMG;
        dev_hist(b >> 3, b & 7, prev_hist, prev_hist_ln, word_emb, pos_emb,
                 type_emb, ln_g, ln_b, hist_parts, smem);
    } else if (bid < F1_CONV) {
        int b = bid - F1_HIST;
        if (b < 384)      dev_conv(W_e2h, Wt_e2h, EMB, HID, b & 15, b >> 4, smem);
        else if (b < 640) { int c = b - 384; dev_conv(W_mm, Wt_mm, HID, HID, c & 15, c >> 4, smem); }
        else              { int c = b - 640; dev_conv(W_a1, Wt_a1, HID, ATT, c & 7, c >> 3, smem); }
    } else {
        int r0 = ((bid - F1_CONV) * 4 + (threadIdx.x >> 6)) * 2;
        dev_embed2(r0, input_text, word_emb, pos_emb, type_emb, ln_g, ln_b, reps_bf);
    }
}

// D2: mfma e2h(512) | thin img2 AMODE1(16) | thin hist AMODE2(144)
#define D2_MF   512
#define D2_IMG2 (D2_MF + 16)
#define D2_HG   (D2_IMG2 + 144)
__global__ __launch_bounds__(256)
void uber_gemm1(const bf16_t* reps_bf, const bf16_t* Wt_e2h, const float* b_e2h,
                bf16_t* input_reps,
                const float* partA, const float* b_img, const float* W_mm,
                float* partC,
                const float* hist_parts, const int* prev_hist_ln,
                const float* W_hist, float* partB) {
    __shared__ __align__(16) char smem[33792];
    int bid = blockIdx.x;
    if (bid < D2_MF) {
        dev_mfma<1, true, false, false>(bid & 3, bid >> 2, reps_bf, Wt_e2h, b_e2h,
                                        nullptr, input_reps, nullptr, nullptr,
                                        NROWS, HID, EMB, smem);
    } else if (bid < D2_IMG2) {
        int l = bid - D2_MF;   // 16: (2n,2m,4z)
        dev_thin<1>(l & 1, (l >> 1) & 1, l >> 2, nullptr, 0,
                    partA, (size_t)MPS * HID, b_img, nullptr,
                    W_mm + (size_t)HID * HID, HID, partC, BB, HID, smem);
    } else {
        int l = bid - D2_IMG2; // 144: (2n,12m,6z)
        int l2 = l >> 1;
        dev_thin<2>(l & 1, l2 % 12, l2 / 12, nullptr, 0,
                    hist_parts, (size_t)BB * SS * EMB, nullptr, prev_hist_ln,
                    W_hist, HID, partB, BB * SS, HID, smem);
    }
}

// D3: mfma mm with ROWADD4
__global__ __launch_bounds__(256)
void mfma_mm_k(const bf16_t* input_reps, const bf16_t* Wt_mm, const float* b_mm,
               const float* partC, bf16_t* mm_reps) {
    __shared__ __align__(16) char smem[33792];
    dev_mfma<1, true, true, false>(blockIdx.x & 3, blockIdx.x >> 2, input_reps,
                                   Wt_mm, b_mm, partC, mm_reps, nullptr, nullptr,
                                   NROWS, HID, HID, smem);
}

// D4: mfma a1 + fused tanh/att-dot
__global__ __launch_bounds__(256)
void mfma_a1_k(const bf16_t* mm_reps, const bf16_t* Wt_a1, const float* b_a1,
               const float* W_a2, float* att_part) {
    __shared__ __align__(16) char smem[33792];
    dev_mfma<2, false, false, true>(blockIdx.x & 1, blockIdx.x >> 1, mm_reps,
                                    Wt_a1, b_a1, nullptr, nullptr, W_a2, att_part,
                                    NROWS, ATT, HID, smem);
}

// D5: attend (256) + sep fuse (32)
__global__ void attend_sep(const float* __restrict__ att_part,
                           const unsigned char* __restrict__ masks,
                           const float* __restrict__ b2,
                           const bf16_t* __restrict__ mm,
                           const float* __restrict__ pA,
                           const float* __restrict__ pB,
                           const float* __restrict__ b_sep,
                           const float* __restrict__ b_hist,
                           const int* __restrict__ lens,
                           float* __restrict__ xcat) {
    int bid = blockIdx.x;
    int tid = threadIdx.x, wid = tid >> 6, lane = tid & 63;
    __shared__ float wsm[LL];
    __shared__ float arr[4];
    __shared__ float red[4][64];
    if (bid < 256) {
        int b = bid >> 3, hc = bid & 7;
        int l0 = tid, l1 = tid + 256;
        float v0 = att_part[b * LL + l0] + att_part[(size_t)NROWS + b * LL + l0] + b2[0];
        float v1 = att_part[b * LL + l1] + att_part[(size_t)NROWS + b * LL + l1] + b2[0];
        if (masks[b * LL + l0]) v0 = -INFINITY;
        if (masks[b * LL + l1]) v1 = -INFINITY;
        float m = wave_max(fmaxf(v0, v1));
        if (lane == 0) arr[wid] = m;
        __syncthreads();
        float M = fmaxf(fmaxf(arr[0], arr[1]), fmaxf(arr[2], arr[3]));
        float e0 = expf(v0 - M), e1 = expf(v1 - M);
        wsm[l0] = e0; wsm[l1] = e1;
        float s = wave_sum(e0 + e1);
        __syncthreads();
        if (lane == 0) arr[wid] = s;
        __syncthreads();
        float inv = 1.0f / (arr[0] + arr[1] + arr[2] + arr[3]);
        int h = hc * 64 + lane;
        const bf16_t* base = mm + (size_t)b * LL * HID + h;
        float acc = 0.f;
        int ls = wid * 128;
#pragma unroll 4
        for (int l = ls; l < ls + 128; l++)
            acc += (float)base[(size_t)l * HID] * wsm[l];
        red[wid][lane] = acc;
        __syncthreads();
        if (wid == 0)
            xcat[b * 1024 + 512 + h] =
                (red[0][lane] + red[1][lane] + red[2][lane] + red[3][lane]) * inv;
    } else {
        int b = bid - 256;
        const size_t MNa = (size_t)MPS * HID;
        const size_t MNb = (size_t)BB * SS * HID;
        float acc0 = 0.f, acc1 = 0.f;
        for (int s = 0; s < SS; s++) {
            int idx = b * SS + s;
            int len = lens[idx];
            size_t baseA = (size_t)(BB + idx) * HID;
            size_t baseB = (size_t)idx * HID;
            float v0 = b_sep[tid], v1 = b_sep[tid + 256];
#pragma unroll
            for (int ks = 0; ks < 16; ks++) {
                v0 += pA[ks * MNa + baseA + tid];
                v1 += pA[ks * MNa + baseA + tid + 256];
            }
            float c0 = b_hist[tid], c1 = b_hist[tid + 256];
#pragma unroll
            for (int ks = 0; ks < 6; ks++) {
                c0 += pB[ks * MNb + baseB + tid];
                c1 += pB[ks * MNb + baseB + tid + 256];
            }
            c0 = fmaxf(c0, 0.f); c1 = fmaxf(c1, 0.f);
            if (len <= 0) { c0 = 0.f; c1 = 0.f; }
            float y0 = fmaxf(v0 + c0, 0.f), y1 = fmaxf(v1 + c1, 0.f);
            float ssq = wave_sum(y0 * y0 + y1 * y1);
            if (lane == 0) arr[wid] = ssq;
            __syncthreads();
            float tot = arr[0] + arr[1] + arr[2] + arr[3];
            float inv = 1.0f / fmaxf(sqrtf(tot), 1e-12f);
            acc0 += y0 * inv; acc1 += y1 * inv;
            __syncthreads();
        }
        xcat[b * 1024 + tid] = acc0 * (1.0f / SS);
        xcat[b * 1024 + 256 + tid] = acc1 * (1.0f / SS);
    }
}

// D6: f1 thin GEMM
__global__ __launch_bounds__(256)
void thin_f1_k(const float* xcat, const float* W_f1, float* partD) {
    __shared__ __align__(16) char smem[8192];
    int l = blockIdx.x;  // 32: (2n,2m,8z)
    dev_thin<0>(l & 1, (l >> 1) & 1, l >> 2, xcat, 1024,
                nullptr, 0, nullptr, nullptr, W_f1, HID, partD, BB, HID, smem);
}

// D7: reduce f1 parts + gelu + W_f2 dot
__global__ void final_out2(const float* __restrict__ part,
                           const float* __restrict__ b1,
                           const float* __restrict__ W2,
                           const float* __restrict__ b2,
                           float* __restrict__ out) {
    int b = blockIdx.x;
    int tid = threadIdx.x;
    __shared__ float h[HID];
    const size_t MN = (size_t)BB * HID;
#pragma unroll
    for (int jj = 0; jj < 2; jj++) {
        int d = tid + jj * 256;
        float a = b1[d];
#pragma unroll
        for (int ks = 0; ks < 8; ks++) a += part[ks * MN + (size_t)b * HID + d];
        h[d] = 0.5f * a * (1.0f + erff(a * 0.70710678118654752f));
    }
    __syncthreads();
    float p0 = 0.f, p1 = 0.f;
    for (int j = tid; j < HID; j += 256) {
        float hv = h[j];
        p0 += hv * W2[j * 2 + 0];
        p1 += hv * W2[j * 2 + 1];
    }
    p0 = wave_sum(p0); p1 = wave_sum(p1);
    __shared__ float r0[4], r1[4];
    int wid = tid >> 6;
    if ((tid & 63) == 0) { r0[wid] = p0; r1[wid] = p1; }
    __syncthreads();
    if (tid == 0) {
        out[b * 2 + 0] = r0[0] + r0[1] + r0[2] + r0[3] + b2[0];
        out[b * 2 + 1] = r1[0] + r1[1] + r1[2] + r1[3] + b2[1];
    }
}

// ================= launch =================
extern "C" void kernel_launch(void* const* d_in, const int* in_sizes, int n_in,
                              void* d_out, int out_size, void* d_ws, size_t ws_size,
                              hipStream_t stream) {
    const float* sep_images   = (const float*)d_in[0];
    const float* img_pred     = (const float*)d_in[1];
    const int*   input_text   = (const int*)d_in[2];
    const int*   prev_hist    = (const int*)d_in[3];
    const int*   prev_hist_ln = (const int*)d_in[4];
    const unsigned char* masks = (const unsigned char*)d_in[5];
    const float* word_emb = (const float*)d_in[6];
    const float* pos_emb  = (const float*)d_in[7];
    const float* type_emb = (const float*)d_in[8];
    const float* ln_g = (const float*)d_in[9];
    const float* ln_b = (const float*)d_in[10];
    const float* W_sep = (const float*)d_in[11]; const float* b_sep = (const float*)d_in[12];
    const float* W_e2h = (const float*)d_in[13]; const float* b_e2h = (const float*)d_in[14];
    const float* W_hist = (const float*)d_in[15]; const float* b_hist = (const float*)d_in[16];
    const float* W_img = (const float*)d_in[17]; const float* b_img = (const float*)d_in[18];
    const float* W_mm = (const float*)d_in[19]; const float* b_mm = (const float*)d_in[20];
    const float* W_a1 = (const float*)d_in[21]; const float* b_a1 = (const float*)d_in[22];
    const float* W_a2 = (const float*)d_in[23]; const float* b_a2 = (const float*)d_in[24];
    const float* W_f1 = (const float*)d_in[25]; const float* b_f1 = (const float*)d_in[26];
    const float* W_f2 = (const float*)d_in[27]; const float* b_f2 = (const float*)d_in[28];

    char* ws = (char*)d_ws;
    size_t o = 0;
    auto alloc = [&](size_t bytes) { void* p = ws + o; o += (bytes + 255) & ~(size_t)255; return p; };

    bf16_t* reps_bf     = (bf16_t*)alloc((size_t)NROWS * EMB * 2);
    bf16_t* input_reps  = (bf16_t*)alloc((size_t)NROWS * HID * 2);
    bf16_t* mm_reps     = (bf16_t*)alloc((size_t)NROWS * HID * 2);
    float*  att_part    = (float*)alloc((size_t)2 * NROWS * 4);
    float*  xcat        = (float*)alloc((size_t)BB * 1024 * 4);
    float*  hist_parts  = (float*)alloc((size_t)8 * BB * SS * EMB * 4);
    bf16_t* Wt_e2h      = (bf16_t*)alloc((size_t)EMB * HID * 2);
    bf16_t* Wt_mm       = (bf16_t*)alloc((size_t)HID * HID * 2);
    bf16_t* Wt_a1       = (bf16_t*)alloc((size_t)HID * ATT * 2);
    float*  partA       = (float*)alloc((size_t)16 * MPS * HID * 4);
    float*  partB       = (float*)alloc((size_t)6 * BB * SS * HID * 4);
    float*  partC       = (float*)alloc((size_t)4 * BB * HID * 4);
    float*  partD       = (float*)alloc((size_t)8 * BB * HID * 4);

    // D1: all independent preprocessing (longest jobs first)
    uber_pre<<<F1_EMB, 256, 0, stream>>>(
        input_text, prev_hist, prev_hist_ln, word_emb, pos_emb, type_emb,
        ln_g, ln_b, W_e2h, Wt_e2h, W_mm, Wt_mm, W_a1, Wt_a1,
        img_pred, sep_images, W_img, W_sep, reps_bf, hist_parts, partA);

    // D2: e2h MFMA + img2 + hist GEMMs
    uber_gemm1<<<D2_HG, 256, 0, stream>>>(
        reps_bf, Wt_e2h, b_e2h, input_reps,
        partA, b_img, W_mm, partC,
        hist_parts, prev_hist_ln, W_hist, partB);

    // D3: mm MFMA (+4-way img rowadd)
    mfma_mm_k<<<512, 256, 0, stream>>>(input_reps, Wt_mm, b_mm, partC, mm_reps);

    // D4: a1 MFMA + fused att dot
    mfma_a1_k<<<256, 256, 0, stream>>>(mm_reps, Wt_a1, b_a1, W_a2, att_part);

    // D5: softmax+attend | sep fuse
    attend_sep<<<288, 256, 0, stream>>>(att_part, masks, b_a2, mm_reps,
                                        partA, partB, b_sep, b_hist,
                                        prev_hist_ln, xcat);

    // D6: f1 GEMM
    thin_f1_k<<<32, 256, 0, stream>>>(xcat, W_f1, partD);

    // D7: final
    final_out2<<<BB, 256, 0, stream>>>(partD, b_f1, W_f2, b_f2, (float*)d_out);
}

// Round 15
// 131.919 us; speedup vs baseline: 1.0340x; 1.0340x over previous
//
#include <hip/hip_runtime.h>
#include <hip/hip_bf16.h>
#include <math.h>

// Problem constants
#define VOCAB 30522
#define EMB 768
#define MAXPOS 512
#define HID 512
#define IMG 2048
#define ATT 256
#define BB 32
#define LL 512
#define SS 6
#define HL 128
#define LN_EPS 1e-12f
#define KCH 128
#define NROWS (BB * LL)
#define MPS (BB + BB * SS)   // 224 rows: img_pred(32) + sep_images(192)

typedef __bf16 bf16_t;
typedef __attribute__((ext_vector_type(4))) __bf16 bf16x4;
typedef __attribute__((ext_vector_type(8))) __bf16 bf16x8;
typedef __attribute__((ext_vector_type(4))) float f32x4;

#define AS1 __attribute__((address_space(1)))
#define AS3 __attribute__((address_space(3)))
__device__ __forceinline__ void gload_lds16(const bf16_t* g, bf16_t* l) {
    __builtin_amdgcn_global_load_lds((const AS1 void*)g, (AS3 void*)l, 16, 0, 0);
}

__device__ __forceinline__ float wave_sum(float v) {
    v += __shfl_xor(v, 1);  v += __shfl_xor(v, 2);  v += __shfl_xor(v, 4);
    v += __shfl_xor(v, 8);  v += __shfl_xor(v, 16); v += __shfl_xor(v, 32);
    return v;
}
__device__ __forceinline__ float wave_max(float v) {
    v = fmaxf(v, __shfl_xor(v, 1));  v = fmaxf(v, __shfl_xor(v, 2));
    v = fmaxf(v, __shfl_xor(v, 4));  v = fmaxf(v, __shfl_xor(v, 8));
    v = fmaxf(v, __shfl_xor(v, 16)); v = fmaxf(v, __shfl_xor(v, 32));
    return v;
}

// ================= device building blocks =================

// ---- BERT embed + LN, TWO rows per wave ----
__device__ void dev_embed2(int r0, const int* __restrict__ ids,
                           const float* __restrict__ we, const float* __restrict__ pe,
                           const float* __restrict__ te, const float* __restrict__ g,
                           const float* __restrict__ bta, bf16_t* __restrict__ out) {
    int lane = threadIdx.x & 63;
    int r1 = r0 + 1;
    int id0 = ids[r0], id1 = ids[r1];
    const float* w0 = we + (size_t)id0 * EMB + lane * 12;
    const float* p0 = pe + (size_t)(r0 & (LL - 1)) * EMB + lane * 12;
    const float* w1 = we + (size_t)id1 * EMB + lane * 12;
    const float* p1 = pe + (size_t)(r1 & (LL - 1)) * EMB + lane * 12;
    const float* tp = te + lane * 12;
    float4 a0[3], b0[3], a1[3], b1[3], c[3];
#pragma unroll
    for (int q = 0; q < 3; q++) {
        a0[q] = *(const float4*)(w0 + q * 4);
        a1[q] = *(const float4*)(w1 + q * 4);
        b0[q] = *(const float4*)(p0 + q * 4);
        b1[q] = *(const float4*)(p1 + q * 4);
        c[q]  = *(const float4*)(tp + q * 4);
    }
    const float* gp = g + lane * 12;
    const float* bp = bta + lane * 12;
#pragma unroll
    for (int rr = 0; rr < 2; rr++) {
        float4* av = rr ? a1 : a0;
        float4* bv = rr ? b1 : b0;
        int r = rr ? r1 : r0;
        float x[12]; float s = 0.f, ss = 0.f;
#pragma unroll
        for (int q = 0; q < 3; q++) {
            float v0 = av[q].x + bv[q].x + c[q].x;
            float v1 = av[q].y + bv[q].y + c[q].y;
            float v2 = av[q].z + bv[q].z + c[q].z;
            float v3 = av[q].w + bv[q].w + c[q].w;
            x[q * 4 + 0] = v0; x[q * 4 + 1] = v1;
            x[q * 4 + 2] = v2; x[q * 4 + 3] = v3;
            s += v0 + v1 + v2 + v3;
            ss += v0 * v0 + v1 * v1 + v2 * v2 + v3 * v3;
        }
        s = wave_sum(s); ss = wave_sum(ss);
        float mu = s * (1.0f / EMB);
        float var = ss * (1.0f / EMB) - mu * mu;
        float rs = rsqrtf(var + LN_EPS);
        bf16_t* orow = out + (size_t)r * EMB + lane * 12;
#pragma unroll
        for (int q = 0; q < 3; q++) {
            float4 gv = *(const float4*)(gp + q * 4);
            float4 bb = *(const float4*)(bp + q * 4);
            bf16x4 y;
            y[0] = (bf16_t)(gv.x * (x[q * 4 + 0] - mu) * rs + bb.x);
            y[1] = (bf16_t)(gv.y * (x[q * 4 + 1] - mu) * rs + bb.y);
            y[2] = (bf16_t)(gv.z * (x[q * 4 + 2] - mu) * rs + bb.z);
            y[3] = (bf16_t)(gv.w * (x[q * 4 + 3] - mu) * rs + bb.w);
            *(bf16x4*)(orow + q * 4) = y;
        }
    }
}

// ---- tiled transpose+bf16 of one 32x32 tile ----
__device__ void dev_conv(const float* __restrict__ in, bf16_t* __restrict__ out,
                         int K, int N, int x, int y, char* smem) {
    float (*t)[33] = (float(*)[33])smem;
    int n0 = x * 32, k0 = y * 32;
    int tx = threadIdx.x & 31, ty = threadIdx.x >> 5;
#pragma unroll
    for (int i = 0; i < 4; i++)
        t[ty + i * 8][tx] = in[(size_t)(k0 + ty + i * 8) * N + n0 + tx];
    __syncthreads();
#pragma unroll
    for (int i = 0; i < 4; i++)
        out[(size_t)(n0 + ty + i * 8) * K + k0 + tx] = (bf16_t)t[tx][ty + i * 8];
}

// ---- history embed+LN partial sums, software-pipelined word_emb gather ----
__device__ void dev_hist(int bs, int grp, const int* __restrict__ ids,
                         const int* __restrict__ lens,
                         const float* __restrict__ we, const float* __restrict__ pe,
                         const float* __restrict__ te, const float* __restrict__ g,
                         const float* __restrict__ bta,
                         float* __restrict__ parts, char* smem) {
    float (*acc)[EMB] = (float(*)[EMB])smem;
    int len = lens[bs];
    int tid = threadIdx.x, wid = tid >> 6, lane = tid & 63;
#pragma unroll
    for (int k = 0; k < 12; k++) acc[wid][lane + k * 64] = 0.f;
    float tv[12];
#pragma unroll
    for (int k = 0; k < 12; k++) tv[k] = te[lane + k * 64];
    int h = grp + 8 * wid;
    bool valid = (h < len);
    float xw[12];
    {
        int id = valid ? ids[bs * HL + h] : 0;
        const float* wrow = we + (size_t)id * EMB;
        if (valid) {
#pragma unroll
            for (int k = 0; k < 12; k++) xw[k] = wrow[lane + k * 64];
        }
    }
#pragma unroll
    for (int i = 0; i < 4; i++) {
        int hn = h + 32;
        bool vnext = (i < 3) && (hn < len);
        float yw[12];
        {
            int idn = vnext ? ids[bs * HL + hn] : 0;
            const float* wrown = we + (size_t)idn * EMB;
            if (vnext) {
#pragma unroll
                for (int k = 0; k < 12; k++) yw[k] = wrown[lane + k * 64];
            }
        }
        if (valid) {
            const float* prow = pe + (size_t)h * EMB;
            float x[12]; float s = 0.f, ss = 0.f;
#pragma unroll
            for (int k = 0; k < 12; k++) {
                int j = lane + k * 64;
                float v = xw[k] + prow[j] + tv[k];
                x[k] = v; s += v; ss += v * v;
            }
            s = wave_sum(s); ss = wave_sum(ss);
            float mu = s * (1.0f / EMB);
            float var = ss * (1.0f / EMB) - mu * mu;
            float rs = rsqrtf(var + LN_EPS);
#pragma unroll
            for (int k = 0; k < 12; k++) {
                int j = lane + k * 64;
                acc[wid][j] += g[j] * (x[k] - mu) * rs + bta[j];
            }
        }
#pragma unroll
        for (int k = 0; k < 12; k++) xw[k] = yw[k];
        valid = vnext;
        h = hn;
    }
    __syncthreads();
    float* dst = parts + ((size_t)grp * (BB * SS) + bs) * EMB;
    for (int j = tid; j < EMB; j += 256)
        dst[j] = acc[0][j] + acc[1][j] + acc[2][j] + acc[3][j];
}

// ---- split-K thin GEMM with A-prologue modes (16 rows/block) ----
template <int AMODE>
__device__ void dev_thin(int bx, int by, int bz,
                         const float* __restrict__ A, int lda,
                         const float* __restrict__ parts, size_t MNp,
                         const float* __restrict__ abias,
                         const int* __restrict__ lens,
                         const float* __restrict__ B, int ldb,
                         float* __restrict__ part, int M, int N, char* smem) {
    float (*As)[KCH] = (float(*)[KCH])smem;
    int tid = threadIdx.x;
    int n0 = bx * 256, m0 = by * 16, k0 = bz * KCH;

    if (AMODE == 0) {
#pragma unroll
        for (int i = 0; i < 2; i++) {
            int lin = (i * 256 + tid) * 4;
            int m = lin >> 7, k = lin & (KCH - 1);
            *(float4*)&As[m][k] = *(const float4*)(A + (size_t)(m0 + m) * lda + k0 + k);
        }
    } else if (AMODE == 1) {
#pragma unroll
        for (int i = 0; i < 2; i++) {
            int f = i * 256 + tid;
            int m = f >> 5, kq = (f & 31) * 4;
            int row = m0 + m;
            float4 v = *(const float4*)(abias + k0 + kq);
#pragma unroll
            for (int ks = 0; ks < 16; ks++) {
                float4 p = *(const float4*)(parts + (size_t)ks * MNp +
                                            (size_t)row * 512 + k0 + kq);
                v.x += p.x; v.y += p.y; v.z += p.z; v.w += p.w;
            }
            v.x = fmaxf(v.x, 0.f); v.y = fmaxf(v.y, 0.f);
            v.z = fmaxf(v.z, 0.f); v.w = fmaxf(v.w, 0.f);
            *(float4*)&As[m][kq] = v;
        }
    } else {
#pragma unroll
        for (int i = 0; i < 2; i++) {
            int f = i * 256 + tid;
            int m = f >> 5, kq = (f & 31) * 4;
            int row = m0 + m;
            float invd = 1.0f / fmaxf((float)lens[row], 1.0f);
            float4 v = {};
#pragma unroll
            for (int gg = 0; gg < 8; gg++) {
                float4 p = *(const float4*)(parts + (size_t)gg * MNp +
                                            (size_t)row * EMB + k0 + kq);
                v.x += p.x; v.y += p.y; v.z += p.z; v.w += p.w;
            }
            As[m][kq + 0] = v.x * invd; As[m][kq + 1] = v.y * invd;
            As[m][kq + 2] = v.z * invd; As[m][kq + 3] = v.w * invd;
        }
    }
    __syncthreads();
    int nq = tid & 63, mg = tid >> 6;
    const float* Bp = B + (size_t)k0 * ldb + n0 + nq * 4;
    float4 acc[4] = {};
    for (int kk = 0; kk < KCH; kk += 8) {
        float4 b0 = *(const float4*)(Bp + (size_t)(kk + 0) * ldb);
        float4 b1 = *(const float4*)(Bp + (size_t)(kk + 1) * ldb);
        float4 b2 = *(const float4*)(Bp + (size_t)(kk + 2) * ldb);
        float4 b3 = *(const float4*)(Bp + (size_t)(kk + 3) * ldb);
        float4 b4 = *(const float4*)(Bp + (size_t)(kk + 4) * ldb);
        float4 b5 = *(const float4*)(Bp + (size_t)(kk + 5) * ldb);
        float4 b6 = *(const float4*)(Bp + (size_t)(kk + 6) * ldb);
        float4 b7 = *(const float4*)(Bp + (size_t)(kk + 7) * ldb);
        float4 bv[8] = {b0, b1, b2, b3, b4, b5, b6, b7};
#pragma unroll
        for (int j = 0; j < 8; j++) {
#pragma unroll
            for (int mi = 0; mi < 4; mi++) {
                float a = As[mg * 4 + mi][kk + j];
                acc[mi].x += a * bv[j].x; acc[mi].y += a * bv[j].y;
                acc[mi].z += a * bv[j].z; acc[mi].w += a * bv[j].w;
            }
        }
    }
    size_t MN = (size_t)M * N;
#pragma unroll
    for (int mi = 0; mi < 4; mi++)
        *(float4*)(part + (size_t)bz * MN +
                   (size_t)(m0 + mg * 4 + mi) * N + n0 + nq * 4) = acc[mi];
}

// ---- MFMA bf16 GEMM 128x128 tile, BK=64, gload_lds + dbuf, 1 barrier/64K ----
// LDS: As[2][128*64] (32KB), Bs[2][128*64] (32KB), attp (1KB, FUSE_ATT only).
// Slot swizzle (8x16B slots/row): phys p holds global slot p^(r&7); read applies same XOR.
template <int ACT, bool OBF16, bool ROWADD4, bool FUSE_ATT>
__device__ void dev_mfma(int bx, int by,
                         const bf16_t* __restrict__ A, const bf16_t* __restrict__ Bt,
                         const float* __restrict__ bias,
                         const float* __restrict__ rowadd,
                         void* __restrict__ Cv,
                         const float* __restrict__ w2, float* __restrict__ att_part,
                         int M, int N, int K, char* smem) {
    bf16_t* As = (bf16_t*)smem;                 // [2][8192]
    bf16_t* Bs = (bf16_t*)(smem + 32768);       // [2][8192]
    float (*attp)[2] = (float(*)[2])(smem + 65536);
    int tid = threadIdx.x;
    int lane = tid & 63, wid = tid >> 6;
    int wr = wid >> 1, wc = wid & 1;
    int row0 = by * 128, col0 = bx * 128;

    int lsub = lane >> 3;                 // row-within-8 (also r&7)
    int ssrc = ((lane & 7) ^ lsub) << 3;  // pre-swizzled source k-offset

    const bf16_t* Ag = A + (size_t)row0 * K;
    const bf16_t* Bg = Bt + (size_t)col0 * K;

    f32x4 acc[4][4] = {};
    int lrow = lane & 15;
    int g8 = lane >> 4;

    auto stage_pair = [&](int buf, int kb) {
#pragma unroll
        for (int j = 0; j < 4; j++) {
            int r = wid * 32 + j * 8 + lsub;
            gload_lds16(Ag + (size_t)r * K + kb + ssrc,
                        As + buf * 8192 + wid * 2048 + j * 512);
            gload_lds16(Bg + (size_t)r * K + kb + ssrc,
                        Bs + buf * 8192 + wid * 2048 + j * 512);
        }
    };

    stage_pair(0, 0);
    __syncthreads();
    int cur = 0;
    for (int kb = 0; kb < K; kb += 64) {
        if (kb + 64 < K) stage_pair(cur ^ 1, kb + 64);
#pragma unroll
        for (int kh = 0; kh < 2; kh++) {
            bf16x8 af[4], bfr[4];
#pragma unroll
            for (int mi = 0; mi < 4; mi++) {
                int r = wr * 64 + mi * 16 + lrow;
                int ph = (kh * 4 + g8) ^ (r & 7);
                af[mi] = *(const bf16x8*)(As + cur * 8192 + r * 64 + ph * 8);
            }
#pragma unroll
            for (int ni = 0; ni < 4; ni++) {
                int r = wc * 64 + ni * 16 + lrow;
                int ph = (kh * 4 + g8) ^ (r & 7);
                bfr[ni] = *(const bf16x8*)(Bs + cur * 8192 + r * 64 + ph * 8);
            }
#pragma unroll
            for (int mi = 0; mi < 4; mi++)
#pragma unroll
                for (int ni = 0; ni < 4; ni++)
                    acc[mi][ni] = __builtin_amdgcn_mfma_f32_16x16x32_bf16(
                        af[mi], bfr[ni], acc[mi][ni], 0, 0, 0);
        }
        __syncthreads();
        cur ^= 1;
    }

    if (FUSE_ATT) {
        float w2v[4];
#pragma unroll
        for (int ni = 0; ni < 4; ni++)
            w2v[ni] = w2[col0 + wc * 64 + ni * 16 + lrow];
#pragma unroll
        for (int mi = 0; mi < 4; mi++) {
#pragma unroll
            for (int r = 0; r < 4; r++) {
                float s = 0.f;
#pragma unroll
                for (int ni = 0; ni < 4; ni++) {
                    int col = col0 + wc * 64 + ni * 16 + lrow;
                    float v = tanhf(acc[mi][ni][r] + bias[col]);
                    s += v * w2v[ni];
                }
                s += __shfl_xor(s, 1); s += __shfl_xor(s, 2);
                s += __shfl_xor(s, 4); s += __shfl_xor(s, 8);
                if ((lane & 15) == 0)
                    attp[wr * 64 + mi * 16 + (lane >> 4) * 4 + r][wc] = s;
            }
        }
        __syncthreads();
        if (tid < 128)
            att_part[(size_t)bx * M + row0 + tid] = attp[tid][0] + attp[tid][1];
        return;
    }

    float* Cf = (float*)Cv;
    bf16_t* Cb = (bf16_t*)Cv;
    int rg = (lane >> 4) * 4;
#pragma unroll
    for (int mi = 0; mi < 4; mi++) {
#pragma unroll
        for (int ni = 0; ni < 4; ni++) {
            int col = col0 + wc * 64 + ni * 16 + lrow;
#pragma unroll
            for (int r = 0; r < 4; r++) {
                int row = row0 + wr * 64 + mi * 16 + rg + r;
                float v = acc[mi][ni][r] + bias[col];
                if (ROWADD4) {
                    int bslot = row >> 9;
#pragma unroll
                    for (int ks = 0; ks < 4; ks++)
                        v += rowadd[(size_t)ks * BB * HID + (size_t)bslot * HID + col];
                }
                if (ACT == 1) v = fmaxf(v, 0.f);
                if (ACT == 2) v = tanhf(v);
                if (OBF16) Cb[(size_t)row * N + col] = (bf16_t)v;
                else       Cf[(size_t)row * N + col] = v;
            }
        }
    }
}

// ================= dispatch kernels =================

// D1 (longest-job-first): thin-sep(384) | thin-img(64) | hist(1536) | conv(768) | embed(2048)
#define F1_SEP   384
#define F1_IMG   (F1_SEP + 64)     // 448
#define F1_HIST  (F1_IMG + 1536)   // 1984
#define F1_CONV  (F1_HIST + 768)   // 2752
#define F1_EMB   (F1_CONV + 2048)  // 4800
__global__ __launch_bounds__(256)
void uber_pre(const int* input_text, const int* prev_hist, const int* prev_hist_ln,
              const float* word_emb, const float* pos_emb, const float* type_emb,
              const float* ln_g, const float* ln_b,
              const float* W_e2h, bf16_t* Wt_e2h,
              const float* W_mm, bf16_t* Wt_mm,
              const float* W_a1, bf16_t* Wt_a1,
              const float* img_pred, const float* sep_images,
              const float* W_img, const float* W_sep,
              bf16_t* reps_bf, float* hist_parts, float* partA) {
    __shared__ __align__(16) char smem[12288];
    int bid = blockIdx.x;
    if (bid < F1_SEP) {
        int l = bid;
        int l2 = l >> 1;
        dev_thin<0>(l & 1, l2 % 12, l2 / 12, sep_images, IMG,
                    nullptr, 0, nullptr, nullptr, W_sep, HID,
                    partA + (size_t)BB * HID, MPS, HID, smem);
    } else if (bid < F1_IMG) {
        int l = bid - F1_SEP;
        dev_thin<0>(l & 1, (l >> 1) & 1, l >> 2, img_pred, IMG,
                    nullptr, 0, nullptr, nullptr, W_img, HID, partA, MPS, HID, smem);
    } else if (bid < F1_HIST) {
        int b = bid - F1_IMG;
        dev_hist(b >> 3, b & 7, prev_hist, prev_hist_ln, word_emb, pos_emb,
                 type_emb, ln_g, ln_b, hist_parts, smem);
    } else if (bid < F1_CONV) {
        int b = bid - F1_HIST;
        if (b < 384)      dev_conv(W_e2h, Wt_e2h, EMB, HID, b & 15, b >> 4, smem);
        else if (b < 640) { int c = b - 384; dev_conv(W_mm, Wt_mm, HID, HID, c & 15, c >> 4, smem); }
        else              { int c = b - 640; dev_conv(W_a1, Wt_a1, HID, ATT, c & 7, c >> 3, smem); }
    } else {
        int r0 = ((bid - F1_CONV) * 4 + (threadIdx.x >> 6)) * 2;
        dev_embed2(r0, input_text, word_emb, pos_emb, type_emb, ln_g, ln_b, reps_bf);
    }
}

// D2: mfma e2h(512) | thin img2 AMODE1(16) | thin hist AMODE2(144)
#define D2_MF   512
#define D2_IMG2 (D2_MF + 16)
#define D2_HG   (D2_IMG2 + 144)
__global__ __launch_bounds__(256)
void uber_gemm1(const bf16_t* reps_bf, const bf16_t* Wt_e2h, const float* b_e2h,
                bf16_t* input_reps,
                const float* partA, const float* b_img, const float* W_mm,
                float* partC,
                const float* hist_parts, const int* prev_hist_ln,
                const float* W_hist, float* partB) {
    __shared__ __align__(16) char smem[65536];
    int bid = blockIdx.x;
    if (bid < D2_MF) {
        dev_mfma<1, true, false, false>(bid & 3, bid >> 2, reps_bf, Wt_e2h, b_e2h,
                                        nullptr, input_reps, nullptr, nullptr,
                                        NROWS, HID, EMB, smem);
    } else if (bid < D2_IMG2) {
        int l = bid - D2_MF;
        dev_thin<1>(l & 1, (l >> 1) & 1, l >> 2, nullptr, 0,
                    partA, (size_t)MPS * HID, b_img, nullptr,
                    W_mm + (size_t)HID * HID, HID, partC, BB, HID, smem);
    } else {
        int l = bid - D2_IMG2;
        int l2 = l >> 1;
        dev_thin<2>(l & 1, l2 % 12, l2 / 12, nullptr, 0,
                    hist_parts, (size_t)BB * SS * EMB, nullptr, prev_hist_ln,
                    W_hist, HID, partB, BB * SS, HID, smem);
    }
}

// D3: mfma mm with ROWADD4
__global__ __launch_bounds__(256)
void mfma_mm_k(const bf16_t* input_reps, const bf16_t* Wt_mm, const float* b_mm,
               const float* partC, bf16_t* mm_reps) {
    __shared__ __align__(16) char smem[65536];
    dev_mfma<1, true, true, false>(blockIdx.x & 3, blockIdx.x >> 2, input_reps,
                                   Wt_mm, b_mm, partC, mm_reps, nullptr, nullptr,
                                   NROWS, HID, HID, smem);
}

// D4: mfma a1 + fused tanh/att-dot
__global__ __launch_bounds__(256)
void mfma_a1_k(const bf16_t* mm_reps, const bf16_t* Wt_a1, const float* b_a1,
               const float* W_a2, float* att_part) {
    __shared__ __align__(16) char smem[66560];
    dev_mfma<2, false, false, true>(blockIdx.x & 1, blockIdx.x >> 1, mm_reps,
                                    Wt_a1, b_a1, nullptr, nullptr, W_a2, att_part,
                                    NROWS, ATT, HID, smem);
}

// D5: attend (256) + sep fuse (32)
__global__ void attend_sep(const float* __restrict__ att_part,
                           const unsigned char* __restrict__ masks,
                           const float* __restrict__ b2,
                           const bf16_t* __restrict__ mm,
                           const float* __restrict__ pA,
                           const float* __restrict__ pB,
                           const float* __restrict__ b_sep,
                           const float* __restrict__ b_hist,
                           const int* __restrict__ lens,
                           float* __restrict__ xcat) {
    int bid = blockIdx.x;
    int tid = threadIdx.x, wid = tid >> 6, lane = tid & 63;
    __shared__ float wsm[LL];
    __shared__ float arr[4];
    __shared__ float red[4][64];
    if (bid < 256) {
        int b = bid >> 3, hc = bid & 7;
        int l0 = tid, l1 = tid + 256;
        float v0 = att_part[b * LL + l0] + att_part[(size_t)NROWS + b * LL + l0] + b2[0];
        float v1 = att_part[b * LL + l1] + att_part[(size_t)NROWS + b * LL + l1] + b2[0];
        if (masks[b * LL + l0]) v0 = -INFINITY;
        if (masks[b * LL + l1]) v1 = -INFINITY;
        float m = wave_max(fmaxf(v0, v1));
        if (lane == 0) arr[wid] = m;
        __syncthreads();
        float M = fmaxf(fmaxf(arr[0], arr[1]), fmaxf(arr[2], arr[3]));
        float e0 = expf(v0 - M), e1 = expf(v1 - M);
        wsm[l0] = e0; wsm[l1] = e1;
        float s = wave_sum(e0 + e1);
        __syncthreads();
        if (lane == 0) arr[wid] = s;
        __syncthreads();
        float inv = 1.0f / (arr[0] + arr[1] + arr[2] + arr[3]);
        int h = hc * 64 + lane;
        const bf16_t* base = mm + (size_t)b * LL * HID + h;
        float acc = 0.f;
        int ls = wid * 128;
#pragma unroll 4
        for (int l = ls; l < ls + 128; l++)
            acc += (float)base[(size_t)l * HID] * wsm[l];
        red[wid][lane] = acc;
        __syncthreads();
        if (wid == 0)
            xcat[b * 1024 + 512 + h] =
                (red[0][lane] + red[1][lane] + red[2][lane] + red[3][lane]) * inv;
    } else {
        int b = bid - 256;
        const size_t MNa = (size_t)MPS * HID;
        const size_t MNb = (size_t)BB * SS * HID;
        float acc0 = 0.f, acc1 = 0.f;
        for (int s = 0; s < SS; s++) {
            int idx = b * SS + s;
            int len = lens[idx];
            size_t baseA = (size_t)(BB + idx) * HID;
            size_t baseB = (size_t)idx * HID;
            float v0 = b_sep[tid], v1 = b_sep[tid + 256];
#pragma unroll
            for (int ks = 0; ks < 16; ks++) {
                v0 += pA[ks * MNa + baseA + tid];
                v1 += pA[ks * MNa + baseA + tid + 256];
            }
            float c0 = b_hist[tid], c1 = b_hist[tid + 256];
#pragma unroll
            for (int ks = 0; ks < 6; ks++) {
                c0 += pB[ks * MNb + baseB + tid];
                c1 += pB[ks * MNb + baseB + tid + 256];
            }
            c0 = fmaxf(c0, 0.f); c1 = fmaxf(c1, 0.f);
            if (len <= 0) { c0 = 0.f; c1 = 0.f; }
            float y0 = fmaxf(v0 + c0, 0.f), y1 = fmaxf(v1 + c1, 0.f);
            float ssq = wave_sum(y0 * y0 + y1 * y1);
            if (lane == 0) arr[wid] = ssq;
            __syncthreads();
            float tot = arr[0] + arr[1] + arr[2] + arr[3];
            float inv = 1.0f / fmaxf(sqrtf(tot), 1e-12f);
            acc0 += y0 * inv; acc1 += y1 * inv;
            __syncthreads();
        }
        xcat[b * 1024 + tid] = acc0 * (1.0f / SS);
        xcat[b * 1024 + 256 + tid] = acc1 * (1.0f / SS);
    }
}

// D6: f1 thin GEMM
__global__ __launch_bounds__(256)
void thin_f1_k(const float* xcat, const float* W_f1, float* partD) {
    __shared__ __align__(16) char smem[8192];
    int l = blockIdx.x;
    dev_thin<0>(l & 1, (l >> 1) & 1, l >> 2, xcat, 1024,
                nullptr, 0, nullptr, nullptr, W_f1, HID, partD, BB, HID, smem);
}

// D7: reduce f1 parts + gelu + W_f2 dot
__global__ void final_out2(const float* __restrict__ part,
                           const float* __restrict__ b1,
                           const float* __restrict__ W2,
                           const float* __restrict__ b2,
                           float* __restrict__ out) {
    int b = blockIdx.x;
    int tid = threadIdx.x;
    __shared__ float h[HID];
    const size_t MN = (size_t)BB * HID;
#pragma unroll
    for (int jj = 0; jj < 2; jj++) {
        int d = tid + jj * 256;
        float a = b1[d];
#pragma unroll
        for (int ks = 0; ks < 8; ks++) a += part[ks * MN + (size_t)b * HID + d];
        h[d] = 0.5f * a * (1.0f + erff(a * 0.70710678118654752f));
    }
    __syncthreads();
    float p0 = 0.f, p1 = 0.f;
    for (int j = tid; j < HID; j += 256) {
        float hv = h[j];
        p0 += hv * W2[j * 2 + 0];
        p1 += hv * W2[j * 2 + 1];
    }
    p0 = wave_sum(p0); p1 = wave_sum(p1);
    __shared__ float r0[4], r1[4];
    int wid = tid >> 6;
    if ((tid & 63) == 0) { r0[wid] = p0; r1[wid] = p1; }
    __syncthreads();
    if (tid == 0) {
        out[b * 2 + 0] = r0[0] + r0[1] + r0[2] + r0[3] + b2[0];
        out[b * 2 + 1] = r1[0] + r1[1] + r1[2] + r1[3] + b2[1];
    }
}

// ================= launch =================
extern "C" void kernel_launch(void* const* d_in, const int* in_sizes, int n_in,
                              void* d_out, int out_size, void* d_ws, size_t ws_size,
                              hipStream_t stream) {
    const float* sep_images   = (const float*)d_in[0];
    const float* img_pred     = (const float*)d_in[1];
    const int*   input_text   = (const int*)d_in[2];
    const int*   prev_hist    = (const int*)d_in[3];
    const int*   prev_hist_ln = (const int*)d_in[4];
    const unsigned char* masks = (const unsigned char*)d_in[5];
    const float* word_emb = (const float*)d_in[6];
    const float* pos_emb  = (const float*)d_in[7];
    const float* type_emb = (const float*)d_in[8];
    const float* ln_g = (const float*)d_in[9];
    const float* ln_b = (const float*)d_in[10];
    const float* W_sep = (const float*)d_in[11]; const float* b_sep = (const float*)d_in[12];
    const float* W_e2h = (const float*)d_in[13]; const float* b_e2h = (const float*)d_in[14];
    const float* W_hist = (const float*)d_in[15]; const float* b_hist = (const float*)d_in[16];
    const float* W_img = (const float*)d_in[17]; const float* b_img = (const float*)d_in[18];
    const float* W_mm = (const float*)d_in[19]; const float* b_mm = (const float*)d_in[20];
    const float* W_a1 = (const float*)d_in[21]; const float* b_a1 = (const float*)d_in[22];
    const float* W_a2 = (const float*)d_in[23]; const float* b_a2 = (const float*)d_in[24];
    const float* W_f1 = (const float*)d_in[25]; const float* b_f1 = (const float*)d_in[26];
    const float* W_f2 = (const float*)d_in[27]; const float* b_f2 = (const float*)d_in[28];

    char* ws = (char*)d_ws;
    size_t o = 0;
    auto alloc = [&](size_t bytes) { void* p = ws + o; o += (bytes + 255) & ~(size_t)255; return p; };

    bf16_t* reps_bf     = (bf16_t*)alloc((size_t)NROWS * EMB * 2);
    bf16_t* input_reps  = (bf16_t*)alloc((size_t)NROWS * HID * 2);
    bf16_t* mm_reps     = (bf16_t*)alloc((size_t)NROWS * HID * 2);
    float*  att_part    = (float*)alloc((size_t)2 * NROWS * 4);
    float*  xcat        = (float*)alloc((size_t)BB * 1024 * 4);
    float*  hist_parts  = (float*)alloc((size_t)8 * BB * SS * EMB * 4);
    bf16_t* Wt_e2h      = (bf16_t*)alloc((size_t)EMB * HID * 2);
    bf16_t* Wt_mm       = (bf16_t*)alloc((size_t)HID * HID * 2);
    bf16_t* Wt_a1       = (bf16_t*)alloc((size_t)HID * ATT * 2);
    float*  partA       = (float*)alloc((size_t)16 * MPS * HID * 4);
    float*  partB       = (float*)alloc((size_t)6 * BB * SS * HID * 4);
    float*  partC       = (float*)alloc((size_t)4 * BB * HID * 4);
    float*  partD       = (float*)alloc((size_t)8 * BB * HID * 4);

    // D1: all independent preprocessing (longest jobs first)
    uber_pre<<<F1_EMB, 256, 0, stream>>>(
        input_text, prev_hist, prev_hist_ln, word_emb, pos_emb, type_emb,
        ln_g, ln_b, W_e2h, Wt_e2h, W_mm, Wt_mm, W_a1, Wt_a1,
        img_pred, sep_images, W_img, W_sep, reps_bf, hist_parts, partA);

    // D2: e2h MFMA (BK=64) + img2 + hist GEMMs
    uber_gemm1<<<D2_HG, 256, 0, stream>>>(
        reps_bf, Wt_e2h, b_e2h, input_reps,
        partA, b_img, W_mm, partC,
        hist_parts, prev_hist_ln, W_hist, partB);

    // D3: mm MFMA (+4-way img rowadd)
    mfma_mm_k<<<512, 256, 0, stream>>>(input_reps, Wt_mm, b_mm, partC, mm_reps);

    // D4: a1 MFMA + fused att dot
    mfma_a1_k<<<256, 256, 0, stream>>>(mm_reps, Wt_a1, b_a1, W_a2, att_part);

    // D5: softmax+attend | sep fuse
    attend_sep<<<288, 256, 0, stream>>>(att_part, masks, b_a2, mm_reps,
                                        partA, partB, b_sep, b_hist,
                                        prev_hist_ln, xcat);

    // D6: f1 GEMM
    thin_f1_k<<<32, 256, 0, stream>>>(xcat, W_f1, partD);

    // D7: final
    final_out2<<<BB, 256, 0, stream>>>(partD, b_f1, W_f2, b_f2, (float*)d_out);
}